// Round 6
// baseline (1627.986 us; speedup 1.0000x reference)
//
#include <hip/hip_runtime.h>

// VQ-VAE codebook lookup: z_e [32,2048,64] f32, codebook [1024,64] f32.
// Out = concat(z_q [65536*64] f32, indices [65536] written as f32).
// argmin_k ||x - c_k||^2 == argmin_k (c2[k] - 2*x.c_k)  (x2 row-constant).
//
// Round-6 structure: x tile (128 rows) in LDS, read 16-way-broadcast;
// codebook streamed from L1/L2 into registers (16 lanes share each code
// address -> one 64B line per load, pass slice L1-resident). 8 rows x
// 4 codes micro-tile, 1-step-ahead c prefetch, NO barriers in main loop.

#define N_ROWS   65536
#define D        64
#define K_CODES  1024
#define M_TILE   128
#define STRIDE_X 66        // pad: row-group stride 8*66 % 32 = 16 -> 2-way max

__global__ __launch_bounds__(256) void c2_kernel(const float* __restrict__ cb,
                                                 float* __restrict__ c2) {
    int c = blockIdx.x * 256 + threadIdx.x;
    if (c >= K_CODES) return;
    const float4* row = (const float4*)(cb + c * D);
    float s0 = 0.f, s1 = 0.f, s2 = 0.f, s3 = 0.f;
#pragma unroll
    for (int i = 0; i < D / 4; ++i) {
        float4 v = row[i];
        s0 = fmaf(v.x, v.x, s0);
        s1 = fmaf(v.y, v.y, s1);
        s2 = fmaf(v.z, v.z, s2);
        s3 = fmaf(v.w, v.w, s3);
    }
    c2[c] = (s0 + s1) + (s2 + s3);
}

__global__ __launch_bounds__(256, 3) void vq_kernel(const float* __restrict__ z_e,
                                                    const float* __restrict__ cb,
                                                    const float* __restrict__ c2g,
                                                    float* __restrict__ out) {
    __shared__ float xT[M_TILE * STRIDE_X];   // [row][d], 33792 B

    const int tid      = threadIdx.x;
    const int ti       = tid >> 4;   // 0..15 : row group (8 rows)
    const int tj       = tid & 15;   // 0..15 : code group (4 codes)
    const int row_base = blockIdx.x * M_TILE;

    // ---- stage x tile once (coalesced-ish 16B chunks, one-time cost) ----
    {
        const int r = tid >> 1;      // 0..127
        const int h = tid & 1;       // which half of the row
        const float4* src = (const float4*)(z_e + (size_t)(row_base + r) * D) + h * 8;
        float* dstrow = xT + r * STRIDE_X + h * 32;
#pragma unroll
        for (int i = 0; i < 8; ++i)
            *(float4*)(dstrow + 4 * i) = src[i];
    }
    __syncthreads();

    float best[8];
    int   bidx[8];
#pragma unroll
    for (int r = 0; r < 8; ++r) { best[r] = 3.4e38f; bidx[r] = 0; }

    const float* xrow = xT + (8 * ti) * STRIDE_X;

    // ---- 16 passes of 64 codes; this thread owns codes p*64 + tj*4 + c ----
    for (int p = 0; p < 16; ++p) {
        const float* cbp = cb + (size_t)(p * 64 + tj * 4) * D;
        const float4 c2v = *(const float4*)(c2g + p * 64 + tj * 4);

        float acc[8][4];
#pragma unroll
        for (int r = 0; r < 8; ++r)
#pragma unroll
            for (int c = 0; c < 4; ++c) acc[r][c] = 0.f;

        float4 cur[4], nxt[4];
#pragma unroll
        for (int c = 0; c < 4; ++c)
            cur[c] = *(const float4*)(cbp + c * D);

        // fully unrolled: cur/nxt rotation copy-propagates away
#pragma unroll
        for (int step = 0; step < 16; ++step) {
            const int d  = step * 4;
            const int dn = (step < 15) ? d + 4 : d;   // clamped (in-bounds)
#pragma unroll
            for (int c = 0; c < 4; ++c)
                nxt[c] = *(const float4*)(cbp + c * D + dn);
#pragma unroll
            for (int r = 0; r < 8; ++r) {
                const float4 xv = *(const float4*)(xrow + r * STRIDE_X + d);
#pragma unroll
                for (int c = 0; c < 4; ++c) {
                    acc[r][c] = fmaf(xv.x, cur[c].x, acc[r][c]);
                    acc[r][c] = fmaf(xv.y, cur[c].y, acc[r][c]);
                    acc[r][c] = fmaf(xv.z, cur[c].z, acc[r][c]);
                    acc[r][c] = fmaf(xv.w, cur[c].w, acc[r][c]);
                }
            }
#pragma unroll
            for (int c = 0; c < 4; ++c) cur[c] = nxt[c];
        }

        // ---- fused distance + running argmin (strict < : earliest code) ----
        const float c2a[4] = {c2v.x, c2v.y, c2v.z, c2v.w};
#pragma unroll
        for (int c = 0; c < 4; ++c) {
            const int code = p * 64 + tj * 4 + c;
#pragma unroll
            for (int r = 0; r < 8; ++r) {
                const float dist = fmaf(-2.f, acc[r][c], c2a[c]);
                if (dist < best[r]) { best[r] = dist; bidx[r] = code; }
            }
        }
    }

    // ---- merge across the 16 tj lanes of this row group (same wave) ----
#pragma unroll
    for (int off = 1; off < 16; off <<= 1) {
#pragma unroll
        for (int r = 0; r < 8; ++r) {
            const float ob = __shfl_xor(best[r], off);
            const int   oi = __shfl_xor(bidx[r], off);
            if (ob < best[r] || (ob == best[r] && oi < bidx[r])) {
                best[r] = ob; bidx[r] = oi;
            }
        }
    }

    // ---- write z_q (16 lanes x float4 per row, coalesced) and indices ----
#pragma unroll
    for (int r = 0; r < 8; ++r) {
        const int row = row_base + 8 * ti + r;
        const float4 v = *(const float4*)(cb + (size_t)bidx[r] * D + 4 * tj);
        *(float4*)(out + (size_t)row * D + 4 * tj) = v;
    }
    if (tj < 8) out[(size_t)N_ROWS * D + row_base + 8 * ti + tj] = (float)bidx[tj];
}

extern "C" void kernel_launch(void* const* d_in, const int* in_sizes, int n_in,
                              void* d_out, int out_size, void* d_ws, size_t ws_size,
                              hipStream_t stream) {
    const float* z_e = (const float*)d_in[0];
    const float* cb  = (const float*)d_in[1];
    float* out = (float*)d_out;
    float* c2  = (float*)d_ws;  // 1024 floats scratch

    hipLaunchKernelGGL(c2_kernel, dim3(K_CODES / 256), dim3(256), 0, stream, cb, c2);
    hipLaunchKernelGGL(vq_kernel, dim3(N_ROWS / M_TILE), dim3(256), 0, stream,
                       z_e, cb, c2, out);
}

// Round 7
// 147.697 us; speedup vs baseline: 11.0224x; 11.0224x over previous
//
#include <hip/hip_runtime.h>

// VQ-VAE codebook lookup via bf16 MFMA + rigorous exact re-check.
// z_e [65536,64] f32, codebook [1024,64] f32.
// Out = concat(z_q [65536*64] f32, indices [65536] as f32).
//
// score s(n,k) = x.c - 0.5*c2[k]  (= -dist/2 up to row-const x2/2).
// Sweep 1 (MFMA bf16): per-row max score m.  Sweep 2: recompute, record all
// codes with s >= m - DELTA_H (dist within 3.0 of min).  bf16 error bound
// eps_dist <= 2*2^-8*||x||*||c|| < 1.0 << 3.0/2, so the candidate set
// provably contains the exact argmin. 1 candidate -> done; else exact fp32
// distances + first-occurrence tie-break (same class as prior passing rounds).

typedef __attribute__((ext_vector_type(8))) short short8;
typedef __attribute__((ext_vector_type(4))) float f32x4;

#define N_ROWS  65536
#define D       64
#define K_CODES 1024
#define DELTA_H 1.5f          // half of dist-space margin (Delta = 3.0)
#define CAP     16

__device__ __forceinline__ unsigned short f2bf(float f) {
    unsigned u = __builtin_bit_cast(unsigned, f);
    unsigned r = (u + 0x7fffu + ((u >> 16) & 1u)) >> 16;   // RNE
    return (unsigned short)r;
}

__device__ __forceinline__ short8 cvt8(float4 u, float4 v) {
    short8 r;
    r[0] = (short)f2bf(u.x); r[1] = (short)f2bf(u.y);
    r[2] = (short)f2bf(u.z); r[3] = (short)f2bf(u.w);
    r[4] = (short)f2bf(v.x); r[5] = (short)f2bf(v.y);
    r[6] = (short)f2bf(v.z); r[7] = (short)f2bf(v.w);
    return r;
}

// exact fp32 distance (minus row-constant x2): c2k - 2*dot
__device__ __forceinline__ float dist_f32(const float* __restrict__ xr,
                                          const float* __restrict__ cr,
                                          float c2k) {
    float a = 0.f, b = 0.f, c = 0.f, d = 0.f;
#pragma unroll
    for (int i = 0; i < 16; i += 2) {
        const float4 x0 = ((const float4*)xr)[i];
        const float4 c0 = ((const float4*)cr)[i];
        const float4 x1 = ((const float4*)xr)[i + 1];
        const float4 c1 = ((const float4*)cr)[i + 1];
        a = fmaf(x0.x, c0.x, a); b = fmaf(x0.y, c0.y, b);
        c = fmaf(x0.z, c0.z, c); d = fmaf(x0.w, c0.w, d);
        a = fmaf(x1.x, c1.x, a); b = fmaf(x1.y, c1.y, b);
        c = fmaf(x1.z, c1.z, c); d = fmaf(x1.w, c1.w, d);
    }
    const float dot = (a + b) + (c + d);
    return fmaf(-2.f, dot, c2k);
}

// prep: c2[k] = ||c_k||^2 (fp32) and codebook -> bf16 row-major
__global__ __launch_bounds__(256) void prep_kernel(const float* __restrict__ cb,
                                                   float* __restrict__ c2,
                                                   unsigned short* __restrict__ cbb) {
    const int c = blockIdx.x * 256 + threadIdx.x;   // 0..1023
    const float4* row = (const float4*)(cb + (size_t)c * D);
    unsigned short* orow = cbb + (size_t)c * D;
    float s0 = 0.f, s1 = 0.f, s2 = 0.f, s3 = 0.f;
#pragma unroll
    for (int i = 0; i < 16; ++i) {
        const float4 v = row[i];
        s0 = fmaf(v.x, v.x, s0);
        s1 = fmaf(v.y, v.y, s1);
        s2 = fmaf(v.z, v.z, s2);
        s3 = fmaf(v.w, v.w, s3);
        ushort4 o;
        o.x = f2bf(v.x); o.y = f2bf(v.y); o.z = f2bf(v.z); o.w = f2bf(v.w);
        *(ushort4*)(orow + 4 * i) = o;
    }
    c2[c] = (s0 + s1) + (s2 + s3);
}

__global__ __launch_bounds__(256, 2) void vq_kernel(const float* __restrict__ z_e,
                                                    const float* __restrict__ cb,
                                                    const float* __restrict__ c2g,
                                                    const unsigned short* __restrict__ cbb,
                                                    float* __restrict__ out) {
    __shared__ int cnt_s[128];
    __shared__ int ovf_s[128];
    __shared__ int win_s[128];
    __shared__ int cand_s[128][CAP];

    const int tid   = threadIdx.x;
    const int w     = tid >> 6;        // wave 0..3 -> 32 rows each
    const int lane  = tid & 63;
    const int lcol  = lane & 15;       // entity index (row for A, code for B)
    const int lk    = lane >> 4;       // 0..3 -> k-group 8*lk
    const int rbase = blockIdx.x * 128 + w * 32;

    if (tid < 128) { cnt_s[tid] = 0; ovf_s[tid] = 0; }

    // ---- A fragments: rows rbase+rt*16+lcol, k = 32*ks + 8*lk + e ----
    short8 a00, a01, a10, a11;
    {
        const float* p0 = z_e + (size_t)(rbase + lcol) * D + 8 * lk;
        const float* p1 = z_e + (size_t)(rbase + 16 + lcol) * D + 8 * lk;
        float4 u, v;
        u = *(const float4*)(p0);      v = *(const float4*)(p0 + 4);  a00 = cvt8(u, v);
        u = *(const float4*)(p0 + 32); v = *(const float4*)(p0 + 36); a01 = cvt8(u, v);
        u = *(const float4*)(p1);      v = *(const float4*)(p1 + 4);  a10 = cvt8(u, v);
        u = *(const float4*)(p1 + 32); v = *(const float4*)(p1 + 36); a11 = cvt8(u, v);
    }
    __syncthreads();   // cnt_s/ovf_s init visible before sweep-2 atomics

    const unsigned short* bp = cbb + (size_t)lcol * D + 8 * lk;

#define TILE_LOADS(T)                                                        \
    bn0 = *(const short8*)(bp + (size_t)(T) * 1024);                         \
    bn1 = *(const short8*)(bp + (size_t)(T) * 1024 + 32);                    \
    c2n = c2g[(T) * 16 + lcol];

#define TILE_MFMA()                                                          \
    const float sv = -0.5f * c2c;                                            \
    f32x4 acc0 = {sv, sv, sv, sv};                                           \
    f32x4 acc1 = {sv, sv, sv, sv};                                           \
    acc0 = __builtin_amdgcn_mfma_f32_16x16x32_bf16(a00, bc0, acc0, 0, 0, 0); \
    acc0 = __builtin_amdgcn_mfma_f32_16x16x32_bf16(a01, bc1, acc0, 0, 0, 0); \
    acc1 = __builtin_amdgcn_mfma_f32_16x16x32_bf16(a10, bc0, acc1, 0, 0, 0); \
    acc1 = __builtin_amdgcn_mfma_f32_16x16x32_bf16(a11, bc1, acc1, 0, 0, 0);

    // ---- sweep 1: per-row max score ----
    float m00 = -3.4e38f, m01 = -3.4e38f, m02 = -3.4e38f, m03 = -3.4e38f;
    float m10 = -3.4e38f, m11 = -3.4e38f, m12 = -3.4e38f, m13 = -3.4e38f;
    {
        short8 bc0, bc1, bn0, bn1;
        float c2c, c2n;
        TILE_LOADS(0);
        bc0 = bn0; bc1 = bn1; c2c = c2n;
        for (int t = 0; t < 64; ++t) {
            if (t < 63) { TILE_LOADS(t + 1); }
            TILE_MFMA();
            m00 = fmaxf(m00, acc0[0]); m01 = fmaxf(m01, acc0[1]);
            m02 = fmaxf(m02, acc0[2]); m03 = fmaxf(m03, acc0[3]);
            m10 = fmaxf(m10, acc1[0]); m11 = fmaxf(m11, acc1[1]);
            m12 = fmaxf(m12, acc1[2]); m13 = fmaxf(m13, acc1[3]);
            bc0 = bn0; bc1 = bn1; c2c = c2n;
        }
    }

    // reduce maxima over the 16 code-lanes (same lk-group shares rows)
#pragma unroll
    for (int off = 1; off < 16; off <<= 1) {
        m00 = fmaxf(m00, __shfl_xor(m00, off));
        m01 = fmaxf(m01, __shfl_xor(m01, off));
        m02 = fmaxf(m02, __shfl_xor(m02, off));
        m03 = fmaxf(m03, __shfl_xor(m03, off));
        m10 = fmaxf(m10, __shfl_xor(m10, off));
        m11 = fmaxf(m11, __shfl_xor(m11, off));
        m12 = fmaxf(m12, __shfl_xor(m12, off));
        m13 = fmaxf(m13, __shfl_xor(m13, off));
    }
    const float g0 = fminf(fminf(m00, m01), fminf(m02, m03)) - DELTA_H;
    const float g1 = fminf(fminf(m10, m11), fminf(m12, m13)) - DELTA_H;

#define REC(RL, CODE)                                                        \
    {                                                                        \
        const int sl = atomicAdd(&cnt_s[RL], 1);                             \
        if (sl < CAP) cand_s[RL][sl] = (CODE); else ovf_s[RL] = 1;           \
    }

    // ---- sweep 2: recompute (bit-identical), record candidates ----
    {
        short8 bc0, bc1, bn0, bn1;
        float c2c, c2n;
        TILE_LOADS(0);
        bc0 = bn0; bc1 = bn1; c2c = c2n;
        for (int t = 0; t < 64; ++t) {
            if (t < 63) { TILE_LOADS(t + 1); }
            TILE_MFMA();
            const float t0 = fmaxf(fmaxf(acc0[0], acc0[1]), fmaxf(acc0[2], acc0[3]));
            const float t1 = fmaxf(fmaxf(acc1[0], acc1[1]), fmaxf(acc1[2], acc1[3]));
            if (t0 >= g0) {
                const int code = t * 16 + lcol;
                const int rl = w * 32 + 4 * lk;
                if (acc0[0] >= m00 - DELTA_H) REC(rl + 0, code);
                if (acc0[1] >= m01 - DELTA_H) REC(rl + 1, code);
                if (acc0[2] >= m02 - DELTA_H) REC(rl + 2, code);
                if (acc0[3] >= m03 - DELTA_H) REC(rl + 3, code);
            }
            if (t1 >= g1) {
                const int code = t * 16 + lcol;
                const int rl = w * 32 + 16 + 4 * lk;
                if (acc1[0] >= m10 - DELTA_H) REC(rl + 0, code);
                if (acc1[1] >= m11 - DELTA_H) REC(rl + 1, code);
                if (acc1[2] >= m12 - DELTA_H) REC(rl + 2, code);
                if (acc1[3] >= m13 - DELTA_H) REC(rl + 3, code);
            }
            bc0 = bn0; bc1 = bn1; c2c = c2n;
        }
    }
    __syncthreads();

    // ---- epilogue: resolve winner per row (exact fp32 when needed) ----
    if (tid < 128) {
        const int grow = blockIdx.x * 128 + tid;
        const int cnt  = cnt_s[tid];
        int win;
        if (ovf_s[tid] == 0 && cnt == 1) {
            win = cand_s[tid][0];
        } else {
            const float* xr = z_e + (size_t)grow * D;
            float bestd = 3.4e38f;
            int   bi    = K_CODES;
            if (ovf_s[tid]) {
                for (int k = 0; k < K_CODES; ++k) {
                    const float dk = dist_f32(xr, cb + (size_t)k * D, c2g[k]);
                    if (dk < bestd || (dk == bestd && k < bi)) { bestd = dk; bi = k; }
                }
            } else {
                for (int j = 0; j < cnt; ++j) {
                    const int k = cand_s[tid][j];
                    const float dk = dist_f32(xr, cb + (size_t)k * D, c2g[k]);
                    if (dk < bestd || (dk == bestd && k < bi)) { bestd = dk; bi = k; }
                }
            }
            win = bi;
        }
        win_s[tid] = win;
        out[(size_t)N_ROWS * D + grow] = (float)win;
    }
    __syncthreads();

    // ---- z_q gather+write: 2 threads per row, 8 float4 each ----
    {
        const int rl   = tid >> 1;
        const int hf   = tid & 1;
        const int grow = blockIdx.x * 128 + rl;
        const float4* src = (const float4*)(cb + (size_t)win_s[rl] * D) + hf * 8;
        float4*       dst = (float4*)(out + (size_t)grow * D) + hf * 8;
#pragma unroll
        for (int i = 0; i < 8; ++i) dst[i] = src[i];
    }
}

extern "C" void kernel_launch(void* const* d_in, const int* in_sizes, int n_in,
                              void* d_out, int out_size, void* d_ws, size_t ws_size,
                              hipStream_t stream) {
    const float* z_e = (const float*)d_in[0];
    const float* cb  = (const float*)d_in[1];
    float* out = (float*)d_out;
    float*          c2  = (float*)d_ws;                          // 4 KB
    unsigned short* cbb = (unsigned short*)((char*)d_ws + 4096); // 128 KB

    hipLaunchKernelGGL(prep_kernel, dim3(K_CODES / 256), dim3(256), 0, stream,
                       cb, c2, cbb);
    hipLaunchKernelGGL(vq_kernel, dim3(N_ROWS / 128), dim3(256), 0, stream,
                       z_e, cb, c2, cbb, out);
}